// Round 1
// baseline (448.062 us; speedup 1.0000x reference)
//
#include <hip/hip_runtime.h>
#include <stdint.h>
#include <math.h>

// Problem constants (hard-coded in reference)
#define NBBOX 8192
#define FDIM  4096
#define H1DIM 64
#define H2DIM 32
#define NW    16
#define NCOL  1024   // NW * H1DIM

typedef __attribute__((ext_vector_type(8))) _Float16 f16x8;
typedef __attribute__((ext_vector_type(4))) _Float16 f16x4;
typedef __attribute__((ext_vector_type(4))) float    f32x4;

typedef __attribute__((address_space(1))) void* gptr_t;
typedef __attribute__((address_space(3))) void* lptr_t;

// async global->LDS, 16B per lane; LDS dest is wave-uniform base + lane*16
__device__ __forceinline__ void g2l16(const void* g, void* l) {
    __builtin_amdgcn_global_load_lds((gptr_t)(uintptr_t)g,
                                     (lptr_t)(uint32_t)(uintptr_t)l,
                                     16, 0, 0);
}

// ---------------- kernel 1: x fp32 -> fp16 ----------------
__global__ void convert_x(const float* __restrict__ x, _Float16* __restrict__ xh) {
    int gid = blockIdx.x * blockDim.x + threadIdx.x;
    int idx = gid * 8;
    float4 a = *(const float4*)(x + idx);
    float4 b = *(const float4*)(x + idx + 4);
    f16x8 h;
    h[0] = (_Float16)a.x; h[1] = (_Float16)a.y; h[2] = (_Float16)a.z; h[3] = (_Float16)a.w;
    h[4] = (_Float16)b.x; h[5] = (_Float16)b.y; h[6] = (_Float16)b.z; h[7] = (_Float16)b.w;
    *(f16x8*)(xh + idx) = h;
}

// ---------------- kernel 2: gather+transpose W1[words] -> Bt[1024][4096] fp16 ----------------
__global__ void gather_w(const float* __restrict__ W1, const int* __restrict__ words,
                         _Float16* __restrict__ bth) {
    int gid  = blockIdx.x * blockDim.x + threadIdx.x;   // over 1024*4096/4
    int base = gid * 4;
    int n = base >> 12;          // output row (word-slot*64 + col)
    int k = base & 4095;
    int w = words[n >> 6];
    int c = n & 63;
    const float* src = W1 + (size_t)w * FDIM * H1DIM + c;
    f16x4 h;
#pragma unroll
    for (int i = 0; i < 4; ++i)
        h[i] = (_Float16)src[(size_t)(k + i) * H1DIM];
    *(f16x4*)(bth + (size_t)n * FDIM + k) = h;
}

// ---------------- kernel 3: GEMM H1 = relu(x @ Wcat + b1cat), fp16 MFMA ----------------
// 128x128 tile, BK=32, 256 threads = 4 waves (2x2 of 64x64), 16x16x32 MFMA
__global__ __launch_bounds__(256, 2) void gemm_l1(
    const _Float16* __restrict__ xh, const _Float16* __restrict__ bth,
    const float* __restrict__ b1, const int* __restrict__ words,
    float* __restrict__ Hout)
{
    __shared__ _Float16 As[128 * 32];
    __shared__ _Float16 Bs[128 * 32];

    const int mt   = blockIdx.x >> 3;   // 64 M-tiles
    const int nt   = blockIdx.x & 7;    // 8 N-tiles (consecutive bx -> XCD gets fixed nt: B slice L2-resident)
    const int t    = threadIdx.x;
    const int w    = t >> 6;
    const int lane = t & 63;
    const int m0 = mt * 128, n0 = nt * 128;

    f32x4 acc[4][4] = {};

    // staging: wave w covers rows w*16..+15 (issue0) and 64+w*16..+15 (issue1); 4 lanes/row
    const int rs = w * 16 + (lane >> 2);
    const int kc = (lane & 3) * 8;
    _Float16* ldsA0 = &As[w * 512];
    _Float16* ldsA1 = &As[2048 + w * 512];
    _Float16* ldsB0 = &Bs[w * 512];
    _Float16* ldsB1 = &Bs[2048 + w * 512];

    const _Float16* A = xh  + (size_t)m0 * FDIM;
    const _Float16* B = bth + (size_t)n0 * FDIM;

    const int wm = w >> 1, wn = w & 1;
    const int ml = lane & 15;
    const int q8 = (lane >> 4) * 8;

    for (int kt = 0; kt < 128; ++kt) {
        const int k0 = kt * 32;
        g2l16(A + (size_t)rs * FDIM + k0 + kc,        ldsA0);
        g2l16(A + (size_t)(rs + 64) * FDIM + k0 + kc, ldsA1);
        g2l16(B + (size_t)rs * FDIM + k0 + kc,        ldsB0);
        g2l16(B + (size_t)(rs + 64) * FDIM + k0 + kc, ldsB1);
        __syncthreads();   // drains vmcnt (global_load_lds) + barrier

        f16x8 af[4], bfr[4];
#pragma unroll
        for (int i = 0; i < 4; ++i)
            af[i] = *(const f16x8*)&As[(wm * 64 + i * 16 + ml) * 32 + q8];
#pragma unroll
        for (int j = 0; j < 4; ++j)
            bfr[j] = *(const f16x8*)&Bs[(wn * 64 + j * 16 + ml) * 32 + q8];
#pragma unroll
        for (int i = 0; i < 4; ++i)
#pragma unroll
            for (int j = 0; j < 4; ++j)
                acc[i][j] = __builtin_amdgcn_mfma_f32_16x16x32_f16(af[i], bfr[j], acc[i][j], 0, 0, 0);
        __syncthreads();   // protect LDS before next stage
    }

    // epilogue: C/D layout col=lane&15, row=quad*4+reg  [m89-verified]
    const int q = lane >> 4;
#pragma unroll
    for (int j = 0; j < 4; ++j) {
        const int gcol = n0 + wn * 64 + j * 16 + ml;
        const float bias = b1[words[gcol >> 6] * H1DIM + (gcol & 63)];
#pragma unroll
        for (int i = 0; i < 4; ++i) {
            const int grow0 = m0 + wm * 64 + i * 16 + q * 4;
#pragma unroll
            for (int r = 0; r < 4; ++r) {
                float v = acc[i][j][r] + bias;
                Hout[(size_t)(grow0 + r) * NCOL + gcol] = v > 0.f ? v : 0.f;
            }
        }
    }
}

// ---------------- kernel 4: layers 2+3 + sigmoid product (fp32) ----------------
// one wave per bbox row; lanes: j = lane&31 (h2 col), two halves split k
__global__ __launch_bounds__(256) void tail_mlp(
    const float* __restrict__ Hbuf, const int* __restrict__ words,
    const float* __restrict__ W2, const float* __restrict__ b2,
    const float* __restrict__ W3, const float* __restrict__ b3,
    float* __restrict__ out)
{
    __shared__ float W2s[H1DIM * H2DIM];   // 8 KB, per-slot
    const int t    = threadIdx.x;
    const int wid  = t >> 6;
    const int lane = t & 63;
    const int row  = blockIdx.x * 4 + wid;
    const int j    = lane & 31;
    const int hb   = lane & 32;   // 0 or 32: which k-half this lane accumulates

    float prod = 1.f;
    for (int i = 0; i < NW; ++i) {
        const int wv = words[i];
        __syncthreads();
        for (int u = t; u < H1DIM * H2DIM; u += 256)
            W2s[u] = W2[wv * (H1DIM * H2DIM) + u];
        __syncthreads();

        const float hv = Hbuf[(size_t)row * NCOL + i * H1DIM + lane];
        float acc = 0.f;
#pragma unroll
        for (int k = 0; k < 32; ++k) {
            const float xv = __shfl(hv, hb + k);
            acc = fmaf(xv, W2s[(hb + k) * H2DIM + j], acc);
        }
        acc += __shfl_xor(acc, 32);                      // combine k-halves -> h2[j] in all lanes
        float h2 = acc + b2[wv * H2DIM + j];
        h2 = h2 > 0.f ? h2 : 0.f;
        float p = h2 * W3[wv * H2DIM + j];
#pragma unroll
        for (int off = 16; off > 0; off >>= 1)           // reduce over j within each half
            p += __shfl_xor(p, off);
        const float logit = p + b3[wv];
        prod *= 1.f / (1.f + expf(-logit));
    }
    if (lane == 0) out[row] = prod;
}

extern "C" void kernel_launch(void* const* d_in, const int* in_sizes, int n_in,
                              void* d_out, int out_size, void* d_ws, size_t ws_size,
                              hipStream_t stream)
{
    const float* x   = (const float*)d_in[1];
    const int* words = (const int*)  d_in[2];
    const float* W1  = (const float*)d_in[3];
    const float* b1  = (const float*)d_in[4];
    const float* W2  = (const float*)d_in[5];
    const float* b2  = (const float*)d_in[6];
    const float* W3  = (const float*)d_in[7];
    const float* b3  = (const float*)d_in[8];
    float* out = (float*)d_out;

    char* ws = (char*)d_ws;
    _Float16* xh  = (_Float16*)(ws);                         // 8192*4096*2  = 64 MiB
    _Float16* bth = (_Float16*)(ws + 67108864);              // 1024*4096*2  = 8 MiB
    float*    Hb  = (float*)   (ws + 67108864 + 8388608);    // 8192*1024*4  = 32 MiB

    convert_x<<<NBBOX * FDIM / 8 / 256, 256, 0, stream>>>(x, xh);
    gather_w<<<NCOL * FDIM / 4 / 256, 256, 0, stream>>>(W1, words, bth);
    gemm_l1<<<512, 256, 0, stream>>>(xh, bth, b1, words, Hb);
    tail_mlp<<<NBBOX / 4, 256, 0, stream>>>(Hb, words, W2, b2, W3, b3, out);
}

// Round 2
// 341.682 us; speedup vs baseline: 1.3113x; 1.3113x over previous
//
#include <hip/hip_runtime.h>
#include <stdint.h>
#include <math.h>

// Problem constants (hard-coded in reference)
#define NBBOX 8192
#define FDIM  4096
#define H1DIM 64
#define H2DIM 32
#define NW    16
#define NCOL  1024   // NW * H1DIM

typedef __attribute__((ext_vector_type(8))) _Float16 f16x8;
typedef __attribute__((ext_vector_type(4))) float    f32x4;

typedef __attribute__((address_space(1))) void* gptr_t;
typedef __attribute__((address_space(3))) void* lptr_t;

// async global->LDS, 16B per lane; LDS dest is wave-uniform base + lane*16
__device__ __forceinline__ void g2l16(const void* g, void* l) {
    __builtin_amdgcn_global_load_lds((gptr_t)(uintptr_t)g,
                                     (lptr_t)(uint32_t)(uintptr_t)l,
                                     16, 0, 0);
}

// ---------------- kernel 1: x fp32 -> fp16 ----------------
__global__ void convert_x(const float* __restrict__ x, _Float16* __restrict__ xh) {
    int gid = blockIdx.x * blockDim.x + threadIdx.x;
    int idx = gid * 8;
    float4 a = *(const float4*)(x + idx);
    float4 b = *(const float4*)(x + idx + 4);
    f16x8 h;
    h[0] = (_Float16)a.x; h[1] = (_Float16)a.y; h[2] = (_Float16)a.z; h[3] = (_Float16)a.w;
    h[4] = (_Float16)b.x; h[5] = (_Float16)b.y; h[6] = (_Float16)b.z; h[7] = (_Float16)b.w;
    *(f16x8*)(xh + idx) = h;
}

// ---------------- kernel 2: gather+transpose W1[words] -> Bt[1024][4096] fp16 ----------------
// Coalesced both sides via LDS transpose. grid: 16 words x 32 f-tiles(128) = 512 blocks.
__global__ __launch_bounds__(256) void gather_w(
    const float* __restrict__ W1, const int* __restrict__ words,
    uint32_t* __restrict__ bth_u32)   // bth viewed as packed fp16 pairs
{
    __shared__ uint32_t t[64 * 69];   // [c][f/2], pad 69 -> conflict-free
    const int wi = blockIdx.x >> 5;
    const int ft = blockIdx.x & 31;
    const int f0 = ft * 128;
    const int w  = words[wi];
    const int tid  = threadIdx.x;
    const int c    = tid & 63;
    const int fgrp = tid >> 6;       // 0..3

    const float* src = W1 + ((size_t)w * FDIM + f0) * H1DIM + c;
#pragma unroll
    for (int p = 0; p < 16; ++p) {
        const int f = fgrp * 2 + p * 8;          // even f in 0..126
        float v0 = src[(size_t)f * H1DIM];        // coalesced (c contiguous)
        float v1 = src[(size_t)(f + 1) * H1DIM];
        union { _Float16 h[2]; uint32_t u; } pk;
        pk.h[0] = (_Float16)v0; pk.h[1] = (_Float16)v1;
        t[c * 69 + (f >> 1)] = pk.u;
    }
    __syncthreads();
    // write: row n = wi*64+c gets 128 fp16 = 64 uints, coalesced
#pragma unroll
    for (int p = 0; p < 16; ++p) {
        const int cc = p * 4 + (tid >> 6);
        const int fd = tid & 63;
        bth_u32[(size_t)(wi * 64 + cc) * (FDIM / 2) + ft * 64 + fd] = t[cc * 69 + fd];
    }
}

// ---------------- kernel 3: GEMM H1 = relu(x @ Wcat + b1cat), fp16 MFMA ----------------
// 128x128 tile, BK=64 as 2 packed 32-wide panels per barrier pair, 4 waves, 16x16x32 MFMA
__global__ __launch_bounds__(256, 2) void gemm_l1(
    const _Float16* __restrict__ xh, const _Float16* __restrict__ bth,
    const float* __restrict__ b1, const int* __restrict__ words,
    float* __restrict__ Hout)
{
    __shared__ _Float16 As[2][128 * 32];
    __shared__ _Float16 Bs[2][128 * 32];

    const int mt   = blockIdx.x >> 3;   // 64 M-tiles
    const int nt   = blockIdx.x & 7;    // 8 N-tiles (consecutive bx share mt -> A L2/L3 reuse)
    const int t    = threadIdx.x;
    const int w    = t >> 6;
    const int lane = t & 63;
    const int m0 = mt * 128, n0 = nt * 128;

    f32x4 acc[4][4] = {};

    const int rs = w * 16 + (lane >> 2);
    const int kc = (lane & 3) * 8;

    const _Float16* A = xh  + (size_t)m0 * FDIM;
    const _Float16* B = bth + (size_t)n0 * FDIM;

    const int wm = w >> 1, wn = w & 1;
    const int ml = lane & 15;
    const int q8 = (lane >> 4) * 8;

    for (int kt = 0; kt < 64; ++kt) {
        const int k0 = kt * 64;
#pragma unroll
        for (int s = 0; s < 2; ++s) {
            const int kp = k0 + s * 32 + kc;
            g2l16(A + (size_t)rs * FDIM + kp,        &As[s][w * 512]);
            g2l16(A + (size_t)(rs + 64) * FDIM + kp, &As[s][2048 + w * 512]);
            g2l16(B + (size_t)rs * FDIM + kp,        &Bs[s][w * 512]);
            g2l16(B + (size_t)(rs + 64) * FDIM + kp, &Bs[s][2048 + w * 512]);
        }
        __syncthreads();

#pragma unroll
        for (int s = 0; s < 2; ++s) {
            f16x8 af[4], bfr[4];
#pragma unroll
            for (int i = 0; i < 4; ++i)
                af[i] = *(const f16x8*)&As[s][(wm * 64 + i * 16 + ml) * 32 + q8];
#pragma unroll
            for (int j = 0; j < 4; ++j)
                bfr[j] = *(const f16x8*)&Bs[s][(wn * 64 + j * 16 + ml) * 32 + q8];
#pragma unroll
            for (int i = 0; i < 4; ++i)
#pragma unroll
                for (int j = 0; j < 4; ++j)
                    acc[i][j] = __builtin_amdgcn_mfma_f32_16x16x32_f16(af[i], bfr[j], acc[i][j], 0, 0, 0);
        }
        __syncthreads();
    }

    // epilogue: C/D layout col=lane&15, row=quad*4+reg  [m89-verified]
    const int q = lane >> 4;
#pragma unroll
    for (int j = 0; j < 4; ++j) {
        const int gcol = n0 + wn * 64 + j * 16 + ml;
        const float bias = b1[words[gcol >> 6] * H1DIM + (gcol & 63)];
#pragma unroll
        for (int i = 0; i < 4; ++i) {
            const int grow0 = m0 + wm * 64 + i * 16 + q * 4;
#pragma unroll
            for (int r = 0; r < 4; ++r) {
                float v = acc[i][j][r] + bias;
                Hout[(size_t)(grow0 + r) * NCOL + gcol] = v > 0.f ? v : 0.f;
            }
        }
    }
}

// ---------------- kernel 4: layer 2+3 + sigmoid, one word per wave ----------------
// grid: 16 words x 32 row-blocks = 512 blocks x 256 thr. Wave-private LDS h1 tile;
// inner loop pure fma with wave-uniform (s_load) W2 operands. No barriers.
__global__ __launch_bounds__(256) void tail_mlp(
    const float* __restrict__ Hbuf, const int* __restrict__ words,
    const float* __restrict__ W2, const float* __restrict__ b2,
    const float* __restrict__ W3, const float* __restrict__ b3,
    float* __restrict__ sig)   // [NW][NBBOX]
{
    __shared__ float tile[4][64 * 64];   // 64 KB: per-wave 64 rows x 64 k, chunk-swizzled
    const int t    = threadIdx.x;
    const int v    = t >> 6;
    const int lane = t & 63;
    const int wi   = blockIdx.x >> 5;
    const int rb   = blockIdx.x & 31;
    const int r0   = rb * 256 + v * 64;
    const int wv   = words[wi];

    // stage: coalesced read of Hb[r0..r0+63][wi*64..+63] into wave-private tile.
    // chunk c (4 dwords) of row stored at dword offset row*64 + 4*(((c+row)&7)|(c&8))
    {
        const int rr = lane >> 4;
        const int kch = lane & 15;           // chunk index
#pragma unroll
        for (int p = 0; p < 16; ++p) {
            const int row = p * 4 + rr;
            float4 d = *(const float4*)&Hbuf[(size_t)(r0 + row) * NCOL + wi * H1DIM + kch * 4];
            const int pos = ((kch + row) & 7) | (kch & 8);
            *(float4*)&tile[v][row * 64 + pos * 4] = d;
        }
    }
    // wave-private: no __syncthreads needed (compiler inserts lgkmcnt waits)

    const float* W2w = W2 + (size_t)wv * (H1DIM * H2DIM);
    float acc[H2DIM];
#pragma unroll
    for (int j = 0; j < H2DIM; ++j) acc[j] = 0.f;

#pragma unroll
    for (int c = 0; c < 16; ++c) {
        const int pos = ((c + lane) & 7) | (c & 8);
        f32x4 h = *(const f32x4*)&tile[v][lane * 64 + pos * 4];
#pragma unroll
        for (int kk = 0; kk < 4; ++kk) {
            const float hv = h[kk];
            const int k = c * 4 + kk;
#pragma unroll
            for (int j = 0; j < H2DIM; ++j)
                acc[j] = fmaf(hv, W2w[k * H2DIM + j], acc[j]);
        }
    }

    float logit = b3[wv];
#pragma unroll
    for (int j = 0; j < H2DIM; ++j) {
        float h2 = acc[j] + b2[wv * H2DIM + j];
        h2 = h2 > 0.f ? h2 : 0.f;
        logit = fmaf(h2, W3[wv * H2DIM + j], logit);
    }
    sig[(size_t)wi * NBBOX + r0 + lane] = 1.f / (1.f + expf(-logit));
}

// ---------------- kernel 5: product over words ----------------
__global__ void prod_k(const float* __restrict__ sig, float* __restrict__ out) {
    const int r = blockIdx.x * 256 + threadIdx.x;
    float p = 1.f;
#pragma unroll
    for (int wi = 0; wi < NW; ++wi) p *= sig[(size_t)wi * NBBOX + r];
    out[r] = p;
}

extern "C" void kernel_launch(void* const* d_in, const int* in_sizes, int n_in,
                              void* d_out, int out_size, void* d_ws, size_t ws_size,
                              hipStream_t stream)
{
    const float* x   = (const float*)d_in[1];
    const int* words = (const int*)  d_in[2];
    const float* W1  = (const float*)d_in[3];
    const float* b1  = (const float*)d_in[4];
    const float* W2  = (const float*)d_in[5];
    const float* b2  = (const float*)d_in[6];
    const float* W3  = (const float*)d_in[7];
    const float* b3  = (const float*)d_in[8];
    float* out = (float*)d_out;

    char* ws = (char*)d_ws;
    _Float16* xh  = (_Float16*)(ws);                         // 8192*4096*2  = 64 MiB
    _Float16* bth = (_Float16*)(ws + 67108864);              // 1024*4096*2  = 8 MiB
    float*    Hb  = (float*)   (ws + 67108864 + 8388608);    // 8192*1024*4  = 32 MiB
    float*    sig = (float*)   (ws);                         // aliases xh (dead after gemm)

    convert_x<<<NBBOX * FDIM / 8 / 256, 256, 0, stream>>>(x, xh);
    gather_w<<<512, 256, 0, stream>>>(W1, words, (uint32_t*)bth);
    gemm_l1<<<512, 256, 0, stream>>>(xh, bth, b1, words, Hb);
    tail_mlp<<<512, 256, 0, stream>>>(Hb, words, W2, b2, W3, b3, sig);
    prod_k<<<NBBOX / 256, 256, 0, stream>>>(sig, out);
}